// Round 10
// baseline (2329.652 us; speedup 1.0000x reference)
//
#include <hip/hip_runtime.h>
#include <hip/hip_bf16.h>

typedef __attribute__((ext_vector_type(8))) short short8;
typedef __attribute__((ext_vector_type(4))) float f32x4;
typedef __attribute__((ext_vector_type(2))) float f32x2;
typedef __attribute__((ext_vector_type(4))) unsigned short us4;

#define KEEPF(x) asm volatile("" :: "v"(x))

// ---- workspace layout (bytes) ----
#define WS_ZE     0u
#define WS_ZELO   (1u<<20)
#define WS_B1H    (2u<<20)
#define WS_B1L    (3u<<20)
#define WS_B2     (4u<<20)
#define WS_ZN2    (5u<<20)
#define WS_BS2    ((5u<<20)+32768u)
#define WS_ZQP    (6u<<20)

__device__ __forceinline__ unsigned short f2bf(float x) {
  __hip_bfloat16 h = __float2bfloat16(x);
  return __builtin_bit_cast(unsigned short, h);
}
__device__ __forceinline__ float bf2f(unsigned short u) {
  union { unsigned int i; float f; } x; x.i = ((unsigned int)u) << 16; return x.f;
}

// ---------------- prep: ze -> bf16 hi/lo + row norms ----------------
__global__ __launch_bounds__(256) void prep_ze_k(const float* __restrict__ ze,
                                                 char* __restrict__ ws) {
  int t = blockIdx.x * 256 + threadIdx.x;
  if (t >= 8 * 1024) return;
  const f32x4* row = (const f32x4*)(ze + t * 64);
  unsigned short* dh = (unsigned short*)(ws + WS_ZE) + t * 64;
  unsigned short* dl = (unsigned short*)(ws + WS_ZELO) + t * 64;
  float s = 0.f;
#pragma unroll
  for (int c = 0; c < 8; ++c) {
    const f32x4 v0 = row[2 * c], v1 = row[2 * c + 1];
    union { unsigned short u[8]; short8 v; } H, L;
#pragma unroll
    for (int r = 0; r < 4; ++r) {
      float a = v0[r]; s += a * a;
      unsigned short h = f2bf(a); H.u[r] = h; L.u[r] = f2bf(a - bf2f(h));
      float b = v1[r]; s += b * b;
      unsigned short h2 = f2bf(b); H.u[4 + r] = h2; L.u[4 + r] = f2bf(b - bf2f(h2));
    }
    *(short8*)(dh + c * 8) = H.v;
    *(short8*)(dl + c * 8) = L.v;
  }
  ((float*)(ws + WS_ZN2))[t] = s;
}

// ---------------- prep: book norms + precision ----------------
__global__ __launch_bounds__(256) void prep_bnorm_k(const float* __restrict__ books,
                                                    const float* __restrict__ lpq,
                                                    char* __restrict__ ws,
                                                    float* __restrict__ d_out) {
  int t = blockIdx.x * 256 + threadIdx.x;
  if (t == 0) d_out[524288] = 0.5f / fmaxf(expf(lpq[0]), 1e-10f);
  if (t >= 16 * 512) return;
  const f32x4* row = (const f32x4*)(books + t * 64);
  float s = 0.f;
#pragma unroll
  for (int c = 0; c < 16; ++c) {
    const f32x4 v = row[c];
#pragma unroll
    for (int r = 0; r < 4; ++r) s += v[r] * v[r];
  }
  ((float*)(ws + WS_BS2))[t] = s;
}

// ---------------- prep: matmul1 A-frag images ----------------
__global__ __launch_bounds__(256) void prep_b1_k(const float* __restrict__ books,
                                                 char* __restrict__ ws) {
  int t = blockIdx.x * 256 + threadIdx.x;
  const int sl = t & 15, g = (t >> 4) & 3, f = (t >> 6) & 1, tt = (t >> 7) & 31, k = t >> 12;
  const float* src = books + ((k * 512 + tt * 16 + sl) * 64 + f * 32 + g * 8);
  const f32x4 v0 = *(const f32x4*)(src);
  const f32x4 v1 = *(const f32x4*)(src + 4);
  union { unsigned short u[8]; short8 v; } H, L;
#pragma unroll
  for (int r = 0; r < 4; ++r) {
    unsigned short h = f2bf(v0[r]); H.u[r] = h; L.u[r] = f2bf(v0[r] - bf2f(h));
    unsigned short h2 = f2bf(v1[r]); H.u[4 + r] = h2; L.u[4 + r] = f2bf(v1[r] - bf2f(h2));
  }
  const int off = (k * 32 + tt) * 2048 + f * 1024 + (sl + g * 16) * 16;
  *(short8*)(ws + WS_B1H + off) = H.v;
  *(short8*)(ws + WS_B1L + off) = L.v;
}

// ---------------- prep: matmul2 A-frag image ----------------
__global__ __launch_bounds__(256) void prep_b2_k(const float* __restrict__ books,
                                                 char* __restrict__ ws) {
  int t = blockIdx.x * 256 + threadIdx.x;
  const int l15 = t & 15, sub = (t >> 4) & 3, m = (t >> 6) & 3, w = (t >> 8) & 7,
            hh = (t >> 11) & 1, k = t >> 12;
  const float* src = books + ((k * 512 + hh * 256 + w * 32 + sub * 8) * 64 + m * 16 + l15);
  union { unsigned short u[8]; short8 v; } H;
#pragma unroll
  for (int j = 0; j < 8; ++j) H.u[j] = f2bf(src[j * 64]);
  *(short8*)(ws + WS_B2 + k * 65536 + ((hh * 8 + w) * 4 + m) * 1024 + (l15 + sub * 16) * 16) = H.v;
}

// ---------------- zq partial reduce ----------------
__global__ __launch_bounds__(256) void zq_red_k(const char* __restrict__ ws,
                                                float* __restrict__ d_out) {
  int t = blockIdx.x * 256 + threadIdx.x;
  const f32x4 a = *(const f32x4*)(ws + WS_ZQP + t * 16);
  const f32x4 b = *(const f32x4*)(ws + WS_ZQP + (1u << 21) + t * 16);
  *(f32x4*)(d_out + t * 4) = a + b;
}

// ---------------- main (MODE bits: 1=stores, 2=softmax-trans, 4=phaseC, 8=phaseA) ----------------
template<int MODE, int REPS>
__global__ __launch_bounds__(512, 4)
void gvq_main(const float* __restrict__ gum, const float* __restrict__ cprobs,
              const float* __restrict__ lpq, char* __restrict__ ws,
              float* __restrict__ d_out) {
  __shared__ char lds[36864];
  f32x4* scrb = (f32x4*)(lds + 32768);

  const int tid  = threadIdx.x;
  const int lane = tid & 63;
  const int wave = tid >> 6;
  const int l15  = lane & 15;
  const int g4   = lane >> 4;

  const int bid = blockIdx.x;      // 1024 blocks
  const int kg  = bid & 1;
  const int bt  = bid >> 1;
  const int b   = bt >> 6;
  const int n0  = (bt & 63) * 16;

  const float prec  = 0.5f / fmaxf(expf(lpq[0]), 1e-10f);
  const float prec2 = 2.0f * prec;

  const unsigned short* zh = (const unsigned short*)(ws + WS_ZE)   + (b * 1024 + n0 + l15) * 64;
  const unsigned short* zl = (const unsigned short*)(ws + WS_ZELO) + (b * 1024 + n0 + l15) * 64;
  const short8 zf0h = *(const short8*)(zh + g4 * 8);
  const short8 zf1h = *(const short8*)(zh + 32 + g4 * 8);
  const short8 zf0l = *(const short8*)(zl + g4 * 8);
  const short8 zf1l = *(const short8*)(zl + 32 + g4 * 8);
  const float zn2p = ((const float*)(ws + WS_ZN2))[b * 1024 + n0 + l15] * prec;

  const unsigned swzr = (unsigned)(l15 & 7) << 4;

  f32x4 zacc[4];
  const long gbase0 = ((long)(b * 16) * 1024 + (n0 + l15)) * 512 + wave * 64 + g4 * 4;

#pragma unroll 1
  for (int rep = 0; rep < REPS; ++rep) {
#pragma unroll
    for (int m = 0; m < 4; ++m) zacc[m] = (f32x4){0.f, 0.f, 0.f, 0.f};

#pragma unroll 1
    for (int kk = 0; kk < 8; ++kk) {
      const int k = kg * 8 + kk;
      const float cp = cprobs[b * 16 + k];
      const char* b1h = ws + WS_B1H + k * 65536;
      const char* b1l = ws + WS_B1L + k * 65536;
      const char* b2  = ws + WS_B2  + k * 65536;
      const float* bs2k = (const float*)(ws + WS_BS2) + k * 512;
      const long gb = gbase0 + (long)k * 524288;
      char* encb = lds + (kk & 1) * 16384;
      char* encrow = encb + l15 * 1024;
      f32x4* scr = scrb + (kk & 1) * 128;

      // ---- gumbel loads ----
      const float* up = gum + gb;
      f32x4 uu[4];
#pragma unroll
      for (int i = 0; i < 4; ++i) uu[i] = *(const f32x4*)(up + i * 16);

      // ---- phase A: logits (3-term hi/lo bf16 MFMA) ----
      f32x4 lv[4];
      if constexpr (MODE & 8) {
#pragma unroll
        for (int i = 0; i < 4; ++i) {
          const int t = wave * 4 + i;
          const char* bh = b1h + t * 2048 + lane * 16;
          const char* bl = b1l + t * 2048 + lane * 16;
          const short8 a0h = *(const short8*)(bh);
          const short8 a1h = *(const short8*)(bh + 1024);
          const short8 a0l = *(const short8*)(bl);
          const short8 a1l = *(const short8*)(bl + 1024);
          f32x4 c = {0.f, 0.f, 0.f, 0.f};
          c = __builtin_amdgcn_mfma_f32_16x16x32_bf16(a0h, zf0h, c, 0, 0, 0);
          c = __builtin_amdgcn_mfma_f32_16x16x32_bf16(a1h, zf1h, c, 0, 0, 0);
          c = __builtin_amdgcn_mfma_f32_16x16x32_bf16(a0h, zf0l, c, 0, 0, 0);
          c = __builtin_amdgcn_mfma_f32_16x16x32_bf16(a1h, zf1l, c, 0, 0, 0);
          c = __builtin_amdgcn_mfma_f32_16x16x32_bf16(a0l, zf0h, c, 0, 0, 0);
          c = __builtin_amdgcn_mfma_f32_16x16x32_bf16(a1l, zf1h, c, 0, 0, 0);
          const f32x4 bs2v = *(const f32x4*)(bs2k + t * 16 + g4 * 4);
#pragma unroll
          for (int r = 0; r < 4; ++r)
            lv[i][r] = fmaf(c[r], prec2, fmaf(bs2v[r], -prec, -zn2p));
        }
      } else {
#pragma unroll
        for (int i = 0; i < 4; ++i)
#pragma unroll
          for (int r = 0; r < 4; ++r)
            lv[i][r] = (float)(i + r) - uu[i][r] * 0.125f - zn2p;
      }

      // ---- pass 1: gumbel transform + wave-local maxes ----
      float m1w = -1e30f, m2w = -1e30f;
#pragma unroll
      for (int i = 0; i < 4; ++i)
#pragma unroll
        for (int r = 0; r < 4; ++r) {
          float a;
          if constexpr (MODE & 2) {
            const float gg = -__logf(-__logf(uu[i][r] + 1e-10f) + 1e-10f);
            a = (lv[i][r] + gg) * 2.0f;
          } else {
            a = fmaf(uu[i][r], 0.37f, lv[i][r]) * 2.0f;   // cheap stand-in
          }
          uu[i][r] = a;
          m1w = fmaxf(m1w, lv[i][r]);
          m2w = fmaxf(m2w, a);
        }
      m1w = fmaxf(m1w, __shfl_xor(m1w, 16)); m1w = fmaxf(m1w, __shfl_xor(m1w, 32));
      m2w = fmaxf(m2w, __shfl_xor(m2w, 16)); m2w = fmaxf(m2w, __shfl_xor(m2w, 32));

      // ---- pass 2: exps; enc packed to LDS pre-barrier ----
      float z1 = 0.f, z2 = 0.f;
#pragma unroll
      for (int i = 0; i < 4; ++i) {
        us4 ev;
#pragma unroll
        for (int r = 0; r < 4; ++r) {
          float e1, e2;
          if constexpr (MODE & 2) {
            e1 = __expf(lv[i][r] - m1w);
            e2 = __expf(uu[i][r] - m2w);
          } else {
            e1 = lv[i][r] - m1w;
            e2 = uu[i][r] - m2w;
          }
          z1 += e1; z2 += e2;
          ev[r] = f2bf(e2);
        }
        *(us4*)(encrow + (((unsigned)(wave * 128 + i * 32 + g4 * 8)) ^ swzr)) = ev;
      }
      z1 += __shfl_xor(z1, 16); z1 += __shfl_xor(z1, 32);
      z2 += __shfl_xor(z2, 16); z2 += __shfl_xor(z2, 32);
      if (g4 == 0) scr[wave * 16 + l15] = (f32x4){m1w, m2w, z1, z2};
      __syncthreads();

      // ---- merge across waves ----
      float m1, m2, zz1, zz2;
      {
        const f32x4 pa = scr[g4 * 16 + l15];
        const f32x4 pb = scr[(g4 + 4) * 16 + l15];
        m1 = fmaxf(pa.x, pb.x); m2 = fmaxf(pa.y, pb.y);
        m1 = fmaxf(m1, __shfl_xor(m1, 16)); m1 = fmaxf(m1, __shfl_xor(m1, 32));
        m2 = fmaxf(m2, __shfl_xor(m2, 16)); m2 = fmaxf(m2, __shfl_xor(m2, 32));
        if constexpr (MODE & 2) {
          zz1 = pa.z * __expf(pa.x - m1) + pb.z * __expf(pb.x - m1);
          zz2 = pa.w * __expf(pa.y - m2) + pb.w * __expf(pb.y - m2);
        } else {
          zz1 = pa.z + pb.z + m1;
          zz2 = pa.w + pb.w + m2;
        }
        zz1 += __shfl_xor(zz1, 16); zz1 += __shfl_xor(zz1, 32);
        zz2 += __shfl_xor(zz2, 16); zz2 += __shfl_xor(zz2, 32);
      }
      const float c1 = (MODE & 2) ? (m1 + __logf(zz1)) : (m1 + zz1 * 1e-6f);
      const float s2 = cp / zz2;

      // ---- phase C ----
#pragma unroll
      for (int h = 0; h < 2; ++h) {
        const short8 bf = *(const short8*)(encrow +
            (((unsigned)(h * 512 + wave * 64 + g4 * 16)) ^ swzr));
        if constexpr (MODE & 4) {
          f32x4 cacc[4] = {{0,0,0,0},{0,0,0,0},{0,0,0,0},{0,0,0,0}};
#pragma unroll
          for (int m = 0; m < 4; ++m) {
            const short8 af = *(const short8*)(b2 + ((h * 8 + wave) * 4 + m) * 1024 + lane * 16);
            cacc[m] = __builtin_amdgcn_mfma_f32_16x16x32_bf16(af, bf, cacc[m], 0, 0, 0);
          }
          const float fh = ((MODE & 2)
              ? __expf(scr[(h * 4 + (wave >> 1)) * 16 + l15].y - m2)
              : (scr[(h * 4 + (wave >> 1)) * 16 + l15].y - m2)) * s2;
#pragma unroll
          for (int m = 0; m < 4; ++m)
#pragma unroll
            for (int r = 0; r < 4; ++r) zacc[m][r] = fmaf(cacc[m][r], fh, zacc[m][r]);
        } else {
          KEEPF(bf[0]); KEEPF(bf[4]);
        }
      }

      // ---- prob/log_prob stores ----
      float* pp = d_out + 524289 + gb;
      float* pl = pp + 67108864;
#pragma unroll
      for (int i = 0; i < 4; ++i) {
        f32x4 pv, lpv;
#pragma unroll
        for (int r = 0; r < 4; ++r) {
          lpv[r] = lv[i][r] - c1;
          pv[r]  = (MODE & 2) ? __expf(lpv[r]) : (lpv[r] * 0.5f);
        }
        if constexpr (MODE & 1) {
          *(f32x4*)(pp + i * 16) = pv;
          *(f32x4*)(pl + i * 16) = lpv;
        } else {
#pragma unroll
          for (int r = 0; r < 4; ++r) { KEEPF(pv[r]); KEEPF(lpv[r]); }
        }
      }
    }
  }

  // ---- zq cross-wave reduce + partial write ----
  __syncthreads();
#pragma unroll
  for (int m = 0; m < 4; ++m)
    *(f32x4*)(lds + wave * 4096 + l15 * 256 + m * 64 + g4 * 16) = zacc[m];
  __syncthreads();
  const int e = tid * 2;
  f32x2 acc = {0.f, 0.f};
#pragma unroll
  for (int w = 0; w < 8; ++w) acc += *(const f32x2*)(lds + w * 4096 + e * 4);
  *(f32x2*)(ws + WS_ZQP + (unsigned)kg * (1u << 21) +
            (((unsigned)(b * 1024 + n0)) * 64 + e) * 4) = acc;
}

extern "C" void kernel_launch(void* const* d_in, const int* in_sizes, int n_in,
                              void* d_out, int out_size, void* d_ws, size_t ws_size,
                              hipStream_t stream) {
  (void)in_sizes; (void)n_in; (void)out_size; (void)ws_size;
  const float* ze     = (const float*)d_in[0];
  const float* cprobs = (const float*)d_in[1];
  const float* books  = (const float*)d_in[2];
  const float* lpq    = (const float*)d_in[3];
  const float* gum    = (const float*)d_in[4];
  float* out = (float*)d_out;
  char* ws = (char*)d_ws;
  hipLaunchKernelGGL(prep_ze_k,    dim3(32),   dim3(256), 0, stream, ze, ws);
  hipLaunchKernelGGL(prep_bnorm_k, dim3(32),   dim3(256), 0, stream, books, lpq, ws, out);
  hipLaunchKernelGGL(prep_b1_k,    dim3(256),  dim3(256), 0, stream, books, ws);
  hipLaunchKernelGGL(prep_b2_k,    dim3(256),  dim3(256), 0, stream, books, ws);
  // ablation dispatches (garbage writers) — FULL runs LAST and overwrites everything
  hipLaunchKernelGGL((gvq_main<14,2>), dim3(1024), dim3(512), 0, stream, gum, cprobs, lpq, ws, out); // NOSTORE
  hipLaunchKernelGGL((gvq_main<13,2>), dim3(1024), dim3(512), 0, stream, gum, cprobs, lpq, ws, out); // NOSM
  hipLaunchKernelGGL((gvq_main<11,2>), dim3(1024), dim3(512), 0, stream, gum, cprobs, lpq, ws, out); // NOC
  hipLaunchKernelGGL((gvq_main< 7,2>), dim3(1024), dim3(512), 0, stream, gum, cprobs, lpq, ws, out); // NOA
  hipLaunchKernelGGL((gvq_main<15,2>), dim3(1024), dim3(512), 0, stream, gum, cprobs, lpq, ws, out); // FULL
  hipLaunchKernelGGL(zq_red_k,     dim3(512),  dim3(256), 0, stream, ws, out);
}

// Round 11
// 396.648 us; speedup vs baseline: 5.8733x; 5.8733x over previous
//
#include <hip/hip_runtime.h>
#include <hip/hip_bf16.h>

typedef __attribute__((ext_vector_type(8))) short short8;
typedef __attribute__((ext_vector_type(4))) float f32x4;
typedef __attribute__((ext_vector_type(2))) float f32x2;
typedef __attribute__((ext_vector_type(4))) unsigned short us4;

// ---- workspace layout (bytes) ----
#define WS_ZE     0u
#define WS_ZELO   (1u<<20)
#define WS_B1H    (2u<<20)
#define WS_B1L    (3u<<20)
#define WS_B2     (4u<<20)
#define WS_ZN2    (5u<<20)
#define WS_BS2    ((5u<<20)+32768u)
#define WS_ZQP    (6u<<20)

__device__ __forceinline__ unsigned short f2bf(float x) {
  __hip_bfloat16 h = __float2bfloat16(x);
  return __builtin_bit_cast(unsigned short, h);
}
__device__ __forceinline__ float bf2f(unsigned short u) {
  union { unsigned int i; float f; } x; x.i = ((unsigned int)u) << 16; return x.f;
}
// LDS-only barrier: does NOT drain vmcnt -> global stores stay in flight
__device__ __forceinline__ void lds_barrier() {
  asm volatile("s_waitcnt lgkmcnt(0)" ::: "memory");
  __builtin_amdgcn_s_barrier();
}

// ---------------- prep: ze -> bf16 hi/lo + row norms ----------------
__global__ __launch_bounds__(256) void prep_ze_k(const float* __restrict__ ze,
                                                 char* __restrict__ ws) {
  int t = blockIdx.x * 256 + threadIdx.x;
  if (t >= 8 * 1024) return;
  const f32x4* row = (const f32x4*)(ze + t * 64);
  unsigned short* dh = (unsigned short*)(ws + WS_ZE) + t * 64;
  unsigned short* dl = (unsigned short*)(ws + WS_ZELO) + t * 64;
  float s = 0.f;
#pragma unroll
  for (int c = 0; c < 8; ++c) {
    const f32x4 v0 = row[2 * c], v1 = row[2 * c + 1];
    union { unsigned short u[8]; short8 v; } H, L;
#pragma unroll
    for (int r = 0; r < 4; ++r) {
      float a = v0[r]; s += a * a;
      unsigned short h = f2bf(a); H.u[r] = h; L.u[r] = f2bf(a - bf2f(h));
      float b = v1[r]; s += b * b;
      unsigned short h2 = f2bf(b); H.u[4 + r] = h2; L.u[4 + r] = f2bf(b - bf2f(h2));
    }
    *(short8*)(dh + c * 8) = H.v;
    *(short8*)(dl + c * 8) = L.v;
  }
  ((float*)(ws + WS_ZN2))[t] = s;
}

// ---------------- prep: book norms + precision ----------------
__global__ __launch_bounds__(256) void prep_bnorm_k(const float* __restrict__ books,
                                                    const float* __restrict__ lpq,
                                                    char* __restrict__ ws,
                                                    float* __restrict__ d_out) {
  int t = blockIdx.x * 256 + threadIdx.x;
  if (t == 0) d_out[524288] = 0.5f / fmaxf(expf(lpq[0]), 1e-10f);
  if (t >= 16 * 512) return;
  const f32x4* row = (const f32x4*)(books + t * 64);
  float s = 0.f;
#pragma unroll
  for (int c = 0; c < 16; ++c) {
    const f32x4 v = row[c];
#pragma unroll
    for (int r = 0; r < 4; ++r) s += v[r] * v[r];
  }
  ((float*)(ws + WS_BS2))[t] = s;
}

// ---------------- prep: matmul1 A-frag images ----------------
__global__ __launch_bounds__(256) void prep_b1_k(const float* __restrict__ books,
                                                 char* __restrict__ ws) {
  int t = blockIdx.x * 256 + threadIdx.x;
  const int sl = t & 15, g = (t >> 4) & 3, f = (t >> 6) & 1, tt = (t >> 7) & 31, k = t >> 12;
  const float* src = books + ((k * 512 + tt * 16 + sl) * 64 + f * 32 + g * 8);
  const f32x4 v0 = *(const f32x4*)(src);
  const f32x4 v1 = *(const f32x4*)(src + 4);
  union { unsigned short u[8]; short8 v; } H, L;
#pragma unroll
  for (int r = 0; r < 4; ++r) {
    unsigned short h = f2bf(v0[r]); H.u[r] = h; L.u[r] = f2bf(v0[r] - bf2f(h));
    unsigned short h2 = f2bf(v1[r]); H.u[4 + r] = h2; L.u[4 + r] = f2bf(v1[r] - bf2f(h2));
  }
  const int off = (k * 32 + tt) * 2048 + f * 1024 + (sl + g * 16) * 16;
  *(short8*)(ws + WS_B1H + off) = H.v;
  *(short8*)(ws + WS_B1L + off) = L.v;
}

// ---------------- prep: matmul2 A-frag image ----------------
__global__ __launch_bounds__(256) void prep_b2_k(const float* __restrict__ books,
                                                 char* __restrict__ ws) {
  int t = blockIdx.x * 256 + threadIdx.x;
  const int l15 = t & 15, sub = (t >> 4) & 3, m = (t >> 6) & 3, w = (t >> 8) & 7,
            hh = (t >> 11) & 1, k = t >> 12;
  const float* src = books + ((k * 512 + hh * 256 + w * 32 + sub * 8) * 64 + m * 16 + l15);
  union { unsigned short u[8]; short8 v; } H;
#pragma unroll
  for (int j = 0; j < 8; ++j) H.u[j] = f2bf(src[j * 64]);
  *(short8*)(ws + WS_B2 + k * 65536 + ((hh * 8 + w) * 4 + m) * 1024 + (l15 + sub * 16) * 16) = H.v;
}

// ---------------- zq partial reduce ----------------
__global__ __launch_bounds__(256) void zq_red_k(const char* __restrict__ ws,
                                                float* __restrict__ d_out) {
  int t = blockIdx.x * 256 + threadIdx.x;
  const f32x4 a = *(const f32x4*)(ws + WS_ZQP + t * 16);
  const f32x4 b = *(const f32x4*)(ws + WS_ZQP + (1u << 21) + t * 16);
  *(f32x4*)(d_out + t * 4) = a + b;
}

// ---------------- main: dual-k, LDS-only barriers ----------------
__global__ __launch_bounds__(512, 4)
void gvq_main(const float* __restrict__ gum, const float* __restrict__ cprobs,
              const float* __restrict__ lpq, char* __restrict__ ws,
              float* __restrict__ d_out) {
  __shared__ char lds[36864];
  f32x4* scrb = (f32x4*)(lds + 32768);   // scr_a [0..127], scr_b [128..255]

  const int tid  = threadIdx.x;
  const int lane = tid & 63;
  const int wave = tid >> 6;
  const int l15  = lane & 15;
  const int g4   = lane >> 4;

  const int bid = blockIdx.x;      // 1024 blocks
  const int kg  = bid & 1;
  const int bt  = bid >> 1;
  const int b   = bt >> 6;
  const int n0  = (bt & 63) * 16;

  const float prec  = 0.5f / fmaxf(expf(lpq[0]), 1e-10f);
  const float prec2 = 2.0f * prec;
  const float C24   = 3.7751345442790977e-11f;   // exp(-24)

  const unsigned short* zh = (const unsigned short*)(ws + WS_ZE)   + (b * 1024 + n0 + l15) * 64;
  const unsigned short* zl = (const unsigned short*)(ws + WS_ZELO) + (b * 1024 + n0 + l15) * 64;
  const short8 zf0h = *(const short8*)(zh + g4 * 8);
  const short8 zf1h = *(const short8*)(zh + 32 + g4 * 8);
  const short8 zf0l = *(const short8*)(zl + g4 * 8);
  const short8 zf1l = *(const short8*)(zl + 32 + g4 * 8);
  const float zn2p = ((const float*)(ws + WS_ZN2))[b * 1024 + n0 + l15] * prec;

  const unsigned swzr = (unsigned)(l15 & 7) << 4;
  char* encrow_a = lds + l15 * 1024;
  char* encrow_b = lds + 16384 + l15 * 1024;

  f32x4 zacc[4] = {{0,0,0,0},{0,0,0,0},{0,0,0,0},{0,0,0,0}};
  const long gbase0 = ((long)(b * 16) * 1024 + (n0 + l15)) * 512 + wave * 64 + g4 * 4;

#pragma unroll 1
  for (int pp = 0; pp < 4; ++pp) {
    const int ka = kg * 8 + pp * 2, kb = ka + 1;
    const float cpa = cprobs[b * 16 + ka];
    const float cpb = cprobs[b * 16 + kb];
    const long gba = gbase0 + (long)ka * 524288;
    const long gbb = gbase0 + (long)kb * 524288;

    // ---- gumbel loads for BOTH k (8 dwordx4 in flight) ----
    f32x4 ua[4], ub[4];
    {
      const float* upa = gum + gba;
      const float* upb = gum + gbb;
#pragma unroll
      for (int i = 0; i < 4; ++i) ua[i] = *(const f32x4*)(upa + i * 16);
#pragma unroll
      for (int i = 0; i < 4; ++i) ub[i] = *(const f32x4*)(upb + i * 16);
    }

    // ---- phase A for both k (independent MFMA chains) ----
    f32x4 la[4], lb[4];
#pragma unroll
    for (int kk2 = 0; kk2 < 2; ++kk2) {
      const int k = kk2 ? kb : ka;
      f32x4* lv = kk2 ? lb : la;
      const char* b1h = ws + WS_B1H + k * 65536;
      const char* b1l = ws + WS_B1L + k * 65536;
      const float* bs2k = (const float*)(ws + WS_BS2) + k * 512;
#pragma unroll
      for (int i = 0; i < 4; ++i) {
        const int t = wave * 4 + i;
        const char* bh = b1h + t * 2048 + lane * 16;
        const char* bl = b1l + t * 2048 + lane * 16;
        const short8 a0h = *(const short8*)(bh);
        const short8 a1h = *(const short8*)(bh + 1024);
        const short8 a0l = *(const short8*)(bl);
        const short8 a1l = *(const short8*)(bl + 1024);
        f32x4 c = {0.f, 0.f, 0.f, 0.f};
        c = __builtin_amdgcn_mfma_f32_16x16x32_bf16(a0h, zf0h, c, 0, 0, 0);
        c = __builtin_amdgcn_mfma_f32_16x16x32_bf16(a1h, zf1h, c, 0, 0, 0);
        c = __builtin_amdgcn_mfma_f32_16x16x32_bf16(a0h, zf0l, c, 0, 0, 0);
        c = __builtin_amdgcn_mfma_f32_16x16x32_bf16(a1h, zf1l, c, 0, 0, 0);
        c = __builtin_amdgcn_mfma_f32_16x16x32_bf16(a0l, zf0h, c, 0, 0, 0);
        c = __builtin_amdgcn_mfma_f32_16x16x32_bf16(a1l, zf1h, c, 0, 0, 0);
        const f32x4 bs2v = *(const f32x4*)(bs2k + t * 16 + g4 * 4);
#pragma unroll
        for (int r = 0; r < 4; ++r)
          lv[i][r] = fmaf(c[r], prec2, fmaf(bs2v[r], -prec, -zn2p));
      }
    }

    // ---- softmax pass for both k: m1 fmax; e1/e2; enc writes; scr ----
    float m1a = -1e30f, m1b = -1e30f;
#pragma unroll
    for (int i = 0; i < 4; ++i)
#pragma unroll
      for (int r = 0; r < 4; ++r) {
        m1a = fmaxf(m1a, la[i][r]);
        m1b = fmaxf(m1b, lb[i][r]);
      }
    m1a = fmaxf(m1a, __shfl_xor(m1a, 16)); m1a = fmaxf(m1a, __shfl_xor(m1a, 32));
    m1b = fmaxf(m1b, __shfl_xor(m1b, 16)); m1b = fmaxf(m1b, __shfl_xor(m1b, 32));

    float z1a = 0.f, z2a = 0.f, z1b = 0.f, z2b = 0.f;
#pragma unroll
    for (int i = 0; i < 4; ++i) {
      us4 eva, evb;
#pragma unroll
      for (int r = 0; r < 4; ++r) {
        // k = ka:  e2 = e1^2 * rcp(L)^2 * exp(-24)   [bound-max softmax]
        const float e1a = __expf(la[i][r] - m1a); z1a += e1a;
        const float La  = 1e-10f - __logf(ua[i][r] + 1e-10f);
        const float ra  = __builtin_amdgcn_rcpf(La);
        const float e2a = (e1a * e1a) * (ra * ra) * C24;
        z2a += e2a; eva[r] = f2bf(e2a);
        const float e1b = __expf(lb[i][r] - m1b); z1b += e1b;
        const float Lb  = 1e-10f - __logf(ub[i][r] + 1e-10f);
        const float rb  = __builtin_amdgcn_rcpf(Lb);
        const float e2b = (e1b * e1b) * (rb * rb) * C24;
        z2b += e2b; evb[r] = f2bf(e2b);
      }
      const unsigned eo = ((unsigned)(wave * 128 + i * 32 + g4 * 8)) ^ swzr;
      *(us4*)(encrow_a + eo) = eva;
      *(us4*)(encrow_b + eo) = evb;
    }
    z1a += __shfl_xor(z1a, 16); z1a += __shfl_xor(z1a, 32);
    z2a += __shfl_xor(z2a, 16); z2a += __shfl_xor(z2a, 32);
    z1b += __shfl_xor(z1b, 16); z1b += __shfl_xor(z1b, 32);
    z2b += __shfl_xor(z2b, 16); z2b += __shfl_xor(z2b, 32);
    if (g4 == 0) {
      scrb[wave * 16 + l15]       = (f32x4){m1a, z1a, z2a, 0.f};
      scrb[128 + wave * 16 + l15] = (f32x4){m1b, z1b, z2b, 0.f};
    }
    lds_barrier();                       // B1: LDS-only, stores stay in flight

    // ---- merges (reuse exp(m1w-m1) for both z1 and z2 scaling) ----
    float m1A, c1A, s2A, m1B, c1B, s2B;
    {
      const f32x4 pa = scrb[g4 * 16 + l15];
      const f32x4 pb = scrb[(g4 + 4) * 16 + l15];
      float m1 = fmaxf(pa.x, pb.x);
      m1 = fmaxf(m1, __shfl_xor(m1, 16)); m1 = fmaxf(m1, __shfl_xor(m1, 32));
      const float ea = __expf(pa.x - m1), eb = __expf(pb.x - m1);
      float zz1 = pa.y * ea + pb.y * eb;
      float zz2 = pa.z * ea * ea + pb.z * eb * eb;
      zz1 += __shfl_xor(zz1, 16); zz1 += __shfl_xor(zz1, 32);
      zz2 += __shfl_xor(zz2, 16); zz2 += __shfl_xor(zz2, 32);
      m1A = m1; c1A = m1 + __logf(zz1); s2A = cpa / zz2;
    }
    {
      const f32x4 pa = scrb[128 + g4 * 16 + l15];
      const f32x4 pb = scrb[128 + (g4 + 4) * 16 + l15];
      float m1 = fmaxf(pa.x, pb.x);
      m1 = fmaxf(m1, __shfl_xor(m1, 16)); m1 = fmaxf(m1, __shfl_xor(m1, 32));
      const float ea = __expf(pa.x - m1), eb = __expf(pb.x - m1);
      float zz1 = pa.y * ea + pb.y * eb;
      float zz2 = pa.z * ea * ea + pb.z * eb * eb;
      zz1 += __shfl_xor(zz1, 16); zz1 += __shfl_xor(zz1, 32);
      zz2 += __shfl_xor(zz2, 16); zz2 += __shfl_xor(zz2, 32);
      m1B = m1; c1B = m1 + __logf(zz1); s2B = cpb / zz2;
    }

    // ---- phase C for both k ----
#pragma unroll
    for (int kk2 = 0; kk2 < 2; ++kk2) {
      const char* b2 = ws + WS_B2 + (kk2 ? kb : ka) * 65536;
      const char* encrow = kk2 ? encrow_b : encrow_a;
      const f32x4* scr = scrb + (kk2 ? 128 : 0);
      const float m1 = kk2 ? m1B : m1A;
      const float s2 = kk2 ? s2B : s2A;
#pragma unroll
      for (int h = 0; h < 2; ++h) {
        const short8 bf = *(const short8*)(encrow +
            (((unsigned)(h * 512 + wave * 64 + g4 * 16)) ^ swzr));
        f32x4 cacc[4] = {{0,0,0,0},{0,0,0,0},{0,0,0,0},{0,0,0,0}};
#pragma unroll
        for (int m = 0; m < 4; ++m) {
          const short8 af = *(const short8*)(b2 + ((h * 8 + wave) * 4 + m) * 1024 + lane * 16);
          cacc[m] = __builtin_amdgcn_mfma_f32_16x16x32_bf16(af, bf, cacc[m], 0, 0, 0);
        }
        const float fw = __expf(scr[(h * 4 + (wave >> 1)) * 16 + l15].x - m1);
        const float fh = fw * fw * s2;
#pragma unroll
        for (int m = 0; m < 4; ++m)
#pragma unroll
          for (int r = 0; r < 4; ++r) zacc[m][r] = fmaf(cacc[m][r], fh, zacc[m][r]);
      }
    }

    // ---- prob/log_prob stores for both k (drain across next pair) ----
#pragma unroll
    for (int kk2 = 0; kk2 < 2; ++kk2) {
      const f32x4* lv = kk2 ? lb : la;
      const float c1 = kk2 ? c1B : c1A;
      float* pp_ = d_out + 524289 + (kk2 ? gbb : gba);
      float* pl_ = pp_ + 67108864;
#pragma unroll
      for (int i = 0; i < 4; ++i) {
        f32x4 pv, lpv;
#pragma unroll
        for (int r = 0; r < 4; ++r) {
          lpv[r] = lv[i][r] - c1;
          pv[r]  = __expf(lpv[r]);
        }
        *(f32x4*)(pp_ + i * 16) = pv;
        *(f32x4*)(pl_ + i * 16) = lpv;
      }
    }
    lds_barrier();                       // B2: protect enc/scr overwrite
  }

  // ---- zq cross-wave reduce + partial write ----
  __syncthreads();
#pragma unroll
  for (int m = 0; m < 4; ++m)
    *(f32x4*)(lds + wave * 4096 + l15 * 256 + m * 64 + g4 * 16) = zacc[m];
  __syncthreads();
  const int e = tid * 2;
  f32x2 acc = {0.f, 0.f};
#pragma unroll
  for (int w = 0; w < 8; ++w) acc += *(const f32x2*)(lds + w * 4096 + e * 4);
  *(f32x2*)(ws + WS_ZQP + (unsigned)kg * (1u << 21) +
            (((unsigned)(b * 1024 + n0)) * 64 + e) * 4) = acc;
}

extern "C" void kernel_launch(void* const* d_in, const int* in_sizes, int n_in,
                              void* d_out, int out_size, void* d_ws, size_t ws_size,
                              hipStream_t stream) {
  (void)in_sizes; (void)n_in; (void)out_size; (void)ws_size;
  const float* ze     = (const float*)d_in[0];
  const float* cprobs = (const float*)d_in[1];
  const float* books  = (const float*)d_in[2];
  const float* lpq    = (const float*)d_in[3];
  const float* gum    = (const float*)d_in[4];
  float* out = (float*)d_out;
  char* ws = (char*)d_ws;
  hipLaunchKernelGGL(prep_ze_k,    dim3(32),   dim3(256), 0, stream, ze, ws);
  hipLaunchKernelGGL(prep_bnorm_k, dim3(32),   dim3(256), 0, stream, books, lpq, ws, out);
  hipLaunchKernelGGL(prep_b1_k,    dim3(256),  dim3(256), 0, stream, books, ws);
  hipLaunchKernelGGL(prep_b2_k,    dim3(256),  dim3(256), 0, stream, books, ws);
  hipLaunchKernelGGL(gvq_main,     dim3(1024), dim3(512), 0, stream, gum, cprobs, lpq, ws, out);
  hipLaunchKernelGGL(zq_red_k,     dim3(512),  dim3(256), 0, stream, ws, out);
}

// Round 12
// 295.102 us; speedup vs baseline: 7.8944x; 1.3441x over previous
//
#include <hip/hip_runtime.h>
#include <hip/hip_bf16.h>

typedef __attribute__((ext_vector_type(8))) short short8;
typedef __attribute__((ext_vector_type(4))) float f32x4;
typedef __attribute__((ext_vector_type(2))) float f32x2;
typedef __attribute__((ext_vector_type(4))) unsigned short us4;

// ---- workspace layout (bytes) ----
#define WS_ZE     0u
#define WS_ZELO   (1u<<20)
#define WS_B1H    (2u<<20)
#define WS_B1L    (3u<<20)
#define WS_B2     (4u<<20)
#define WS_ZN2    (5u<<20)
#define WS_BS2    ((5u<<20)+32768u)
#define WS_ZQP    (6u<<20)

__device__ __forceinline__ unsigned short f2bf(float x) {
  __hip_bfloat16 h = __float2bfloat16(x);
  return __builtin_bit_cast(unsigned short, h);
}
__device__ __forceinline__ float bf2f(unsigned short u) {
  union { unsigned int i; float f; } x; x.i = ((unsigned int)u) << 16; return x.f;
}
// LDS-only barrier: does NOT drain vmcnt -> global stores stay in flight
__device__ __forceinline__ void lds_barrier() {
  asm volatile("s_waitcnt lgkmcnt(0)" ::: "memory");
  __builtin_amdgcn_s_barrier();
}

// ---------------- prep: ze -> bf16 hi/lo + row norms ----------------
__global__ __launch_bounds__(256) void prep_ze_k(const float* __restrict__ ze,
                                                 char* __restrict__ ws) {
  int t = blockIdx.x * 256 + threadIdx.x;
  if (t >= 8 * 1024) return;
  const f32x4* row = (const f32x4*)(ze + t * 64);
  unsigned short* dh = (unsigned short*)(ws + WS_ZE) + t * 64;
  unsigned short* dl = (unsigned short*)(ws + WS_ZELO) + t * 64;
  float s = 0.f;
#pragma unroll
  for (int c = 0; c < 8; ++c) {
    const f32x4 v0 = row[2 * c], v1 = row[2 * c + 1];
    union { unsigned short u[8]; short8 v; } H, L;
#pragma unroll
    for (int r = 0; r < 4; ++r) {
      float a = v0[r]; s += a * a;
      unsigned short h = f2bf(a); H.u[r] = h; L.u[r] = f2bf(a - bf2f(h));
      float b = v1[r]; s += b * b;
      unsigned short h2 = f2bf(b); H.u[4 + r] = h2; L.u[4 + r] = f2bf(b - bf2f(h2));
    }
    *(short8*)(dh + c * 8) = H.v;
    *(short8*)(dl + c * 8) = L.v;
  }
  ((float*)(ws + WS_ZN2))[t] = s;
}

// ---------------- prep: book norms + precision ----------------
__global__ __launch_bounds__(256) void prep_bnorm_k(const float* __restrict__ books,
                                                    const float* __restrict__ lpq,
                                                    char* __restrict__ ws,
                                                    float* __restrict__ d_out) {
  int t = blockIdx.x * 256 + threadIdx.x;
  if (t == 0) d_out[524288] = 0.5f / fmaxf(expf(lpq[0]), 1e-10f);
  if (t >= 16 * 512) return;
  const f32x4* row = (const f32x4*)(books + t * 64);
  float s = 0.f;
#pragma unroll
  for (int c = 0; c < 16; ++c) {
    const f32x4 v = row[c];
#pragma unroll
    for (int r = 0; r < 4; ++r) s += v[r] * v[r];
  }
  ((float*)(ws + WS_BS2))[t] = s;
}

// ---------------- prep: matmul1 A-frag images ----------------
__global__ __launch_bounds__(256) void prep_b1_k(const float* __restrict__ books,
                                                 char* __restrict__ ws) {
  int t = blockIdx.x * 256 + threadIdx.x;
  const int sl = t & 15, g = (t >> 4) & 3, f = (t >> 6) & 1, tt = (t >> 7) & 31, k = t >> 12;
  const float* src = books + ((k * 512 + tt * 16 + sl) * 64 + f * 32 + g * 8);
  const f32x4 v0 = *(const f32x4*)(src);
  const f32x4 v1 = *(const f32x4*)(src + 4);
  union { unsigned short u[8]; short8 v; } H, L;
#pragma unroll
  for (int r = 0; r < 4; ++r) {
    unsigned short h = f2bf(v0[r]); H.u[r] = h; L.u[r] = f2bf(v0[r] - bf2f(h));
    unsigned short h2 = f2bf(v1[r]); H.u[4 + r] = h2; L.u[4 + r] = f2bf(v1[r] - bf2f(h2));
  }
  const int off = (k * 32 + tt) * 2048 + f * 1024 + (sl + g * 16) * 16;
  *(short8*)(ws + WS_B1H + off) = H.v;
  *(short8*)(ws + WS_B1L + off) = L.v;
}

// ---------------- prep: matmul2 A-frag image ----------------
__global__ __launch_bounds__(256) void prep_b2_k(const float* __restrict__ books,
                                                 char* __restrict__ ws) {
  int t = blockIdx.x * 256 + threadIdx.x;
  const int l15 = t & 15, sub = (t >> 4) & 3, m = (t >> 6) & 3, w = (t >> 8) & 7,
            hh = (t >> 11) & 1, k = t >> 12;
  const float* src = books + ((k * 512 + hh * 256 + w * 32 + sub * 8) * 64 + m * 16 + l15);
  union { unsigned short u[8]; short8 v; } H;
#pragma unroll
  for (int j = 0; j < 8; ++j) H.u[j] = f2bf(src[j * 64]);
  *(short8*)(ws + WS_B2 + k * 65536 + ((hh * 8 + w) * 4 + m) * 1024 + (l15 + sub * 16) * 16) = H.v;
}

// ---------------- zq partial reduce ----------------
__global__ __launch_bounds__(256) void zq_red_k(const char* __restrict__ ws,
                                                float* __restrict__ d_out) {
  int t = blockIdx.x * 256 + threadIdx.x;
  const f32x4 a = *(const f32x4*)(ws + WS_ZQP + t * 16);
  const f32x4 b = *(const f32x4*)(ws + WS_ZQP + (1u << 21) + t * 16);
  *(f32x4*)(d_out + t * 4) = a + b;
}

// ---------------- main: single-k, LDS-only barrier, bound-max softmax ----------------
__global__ __launch_bounds__(512, 4)
void gvq_main(const float* __restrict__ gum, const float* __restrict__ cprobs,
              const float* __restrict__ lpq, char* __restrict__ ws,
              float* __restrict__ d_out) {
  __shared__ char lds[36864];
  f32x4* scrb = (f32x4*)(lds + 32768);   // 2 x 128 f32x4 (double-buffered)

  const int tid  = threadIdx.x;
  const int lane = tid & 63;
  const int wave = tid >> 6;
  const int l15  = lane & 15;
  const int g4   = lane >> 4;

  const int bid = blockIdx.x;      // 1024 blocks
  const int kg  = bid & 1;
  const int bt  = bid >> 1;
  const int b   = bt >> 6;
  const int n0  = (bt & 63) * 16;

  const float prec  = 0.5f / fmaxf(expf(lpq[0]), 1e-10f);
  const float prec2 = 2.0f * prec;
  const float C24   = 3.7751345442790977e-11f;   // exp(-24)

  const unsigned short* zh = (const unsigned short*)(ws + WS_ZE)   + (b * 1024 + n0 + l15) * 64;
  const unsigned short* zl = (const unsigned short*)(ws + WS_ZELO) + (b * 1024 + n0 + l15) * 64;
  const short8 zf0h = *(const short8*)(zh + g4 * 8);
  const short8 zf1h = *(const short8*)(zh + 32 + g4 * 8);
  const short8 zf0l = *(const short8*)(zl + g4 * 8);
  const short8 zf1l = *(const short8*)(zl + 32 + g4 * 8);
  const float zn2p = ((const float*)(ws + WS_ZN2))[b * 1024 + n0 + l15] * prec;

  const unsigned swzr = (unsigned)(l15 & 7) << 4;

  f32x4 zacc[4] = {{0,0,0,0},{0,0,0,0},{0,0,0,0},{0,0,0,0}};
  const long gbase0 = ((long)(b * 16) * 1024 + (n0 + l15)) * 512 + wave * 64 + g4 * 4;

#pragma unroll 1
  for (int kk = 0; kk < 8; ++kk) {
    const int k = kg * 8 + kk;
    const float cp = cprobs[b * 16 + k];
    const char* b1h = ws + WS_B1H + k * 65536;
    const char* b1l = ws + WS_B1L + k * 65536;
    const char* b2  = ws + WS_B2  + k * 65536;
    const float* bs2k = (const float*)(ws + WS_BS2) + k * 512;
    const long gb = gbase0 + (long)k * 524288;
    char* encrow = lds + (kk & 1) * 16384 + l15 * 1024;
    f32x4* scr = scrb + (kk & 1) * 128;

    // ---- gumbel loads (consumed in pass 2; covered by phase A + pass 1) ----
    const float* up = gum + gb;
    f32x4 uu[4];
#pragma unroll
    for (int i = 0; i < 4; ++i) uu[i] = *(const f32x4*)(up + i * 16);

    // ---- phase A: logits in registers (3-term hi/lo bf16 MFMA) ----
    f32x4 lv[4];
#pragma unroll
    for (int i = 0; i < 4; ++i) {
      const int t = wave * 4 + i;
      const char* bh = b1h + t * 2048 + lane * 16;
      const char* bl = b1l + t * 2048 + lane * 16;
      const short8 a0h = *(const short8*)(bh);
      const short8 a1h = *(const short8*)(bh + 1024);
      const short8 a0l = *(const short8*)(bl);
      const short8 a1l = *(const short8*)(bl + 1024);
      f32x4 c = {0.f, 0.f, 0.f, 0.f};
      c = __builtin_amdgcn_mfma_f32_16x16x32_bf16(a0h, zf0h, c, 0, 0, 0);
      c = __builtin_amdgcn_mfma_f32_16x16x32_bf16(a1h, zf1h, c, 0, 0, 0);
      c = __builtin_amdgcn_mfma_f32_16x16x32_bf16(a0h, zf0l, c, 0, 0, 0);
      c = __builtin_amdgcn_mfma_f32_16x16x32_bf16(a1h, zf1l, c, 0, 0, 0);
      c = __builtin_amdgcn_mfma_f32_16x16x32_bf16(a0l, zf0h, c, 0, 0, 0);
      c = __builtin_amdgcn_mfma_f32_16x16x32_bf16(a1l, zf1h, c, 0, 0, 0);
      const f32x4 bs2v = *(const f32x4*)(bs2k + t * 16 + g4 * 4);
#pragma unroll
      for (int r = 0; r < 4; ++r)
        lv[i][r] = fmaf(c[r], prec2, fmaf(bs2v[r], -prec, -zn2p));
    }

    // ---- pass 1: wave-local max of lv only (m2 is bound-derived: 2*m1w+24) ----
    float m1w = -1e30f;
#pragma unroll
    for (int i = 0; i < 4; ++i)
#pragma unroll
      for (int r = 0; r < 4; ++r) m1w = fmaxf(m1w, lv[i][r]);
    m1w = fmaxf(m1w, __shfl_xor(m1w, 16));
    m1w = fmaxf(m1w, __shfl_xor(m1w, 32));

    // ---- pass 2: e1 = exp(lv-m1w); e2 = e1^2 * rcp(L)^2 * exp(-24) ----
    float z1 = 0.f, z2 = 0.f;
#pragma unroll
    for (int i = 0; i < 4; ++i) {
      us4 ev;
#pragma unroll
      for (int r = 0; r < 4; ++r) {
        const float e1 = __expf(lv[i][r] - m1w); z1 += e1;
        const float L  = 1e-10f - __logf(uu[i][r] + 1e-10f);
        const float rl = __builtin_amdgcn_rcpf(L);
        const float e2 = (e1 * e1) * (rl * rl) * C24;
        z2 += e2;
        ev[r] = f2bf(e2);
      }
      *(us4*)(encrow + (((unsigned)(wave * 128 + i * 32 + g4 * 8)) ^ swzr)) = ev;
    }
    z1 += __shfl_xor(z1, 16); z1 += __shfl_xor(z1, 32);
    z2 += __shfl_xor(z2, 16); z2 += __shfl_xor(z2, 32);
    if (g4 == 0) scr[wave * 16 + l15] = (f32x4){m1w, z1, z2, 0.f};
    lds_barrier();                 // single per-iter barrier; vmcnt NOT drained

    // ---- merge across waves (ea reused for z1 and z2 scaling) ----
    float m1, c1, s2;
    {
      const f32x4 pa = scr[g4 * 16 + l15];
      const f32x4 pb = scr[(g4 + 4) * 16 + l15];
      m1 = fmaxf(pa.x, pb.x);
      m1 = fmaxf(m1, __shfl_xor(m1, 16)); m1 = fmaxf(m1, __shfl_xor(m1, 32));
      const float ea = __expf(pa.x - m1), eb = __expf(pb.x - m1);
      float zz1 = pa.y * ea + pb.y * eb;
      float zz2 = pa.z * ea * ea + pb.z * eb * eb;
      zz1 += __shfl_xor(zz1, 16); zz1 += __shfl_xor(zz1, 32);
      zz2 += __shfl_xor(zz2, 16); zz2 += __shfl_xor(zz2, 32);
      c1 = m1 + __logf(zz1);
      s2 = cp / zz2;
    }

    // ---- phase C: zqT += booksT . encT; slice correction fw^2 * s2 ----
#pragma unroll
    for (int h = 0; h < 2; ++h) {
      const short8 bf = *(const short8*)(encrow +
          (((unsigned)(h * 512 + wave * 64 + g4 * 16)) ^ swzr));
      f32x4 cacc[4] = {{0,0,0,0},{0,0,0,0},{0,0,0,0},{0,0,0,0}};
#pragma unroll
      for (int m = 0; m < 4; ++m) {
        const short8 af = *(const short8*)(b2 + ((h * 8 + wave) * 4 + m) * 1024 + lane * 16);
        cacc[m] = __builtin_amdgcn_mfma_f32_16x16x32_bf16(af, bf, cacc[m], 0, 0, 0);
      }
      const float fw = __expf(scr[(h * 4 + (wave >> 1)) * 16 + l15].x - m1);
      const float fh = fw * fw * s2;
#pragma unroll
      for (int m = 0; m < 4; ++m)
#pragma unroll
        for (int r = 0; r < 4; ++r) zacc[m][r] = fmaf(cacc[m][r], fh, zacc[m][r]);
    }

    // ---- prob/log_prob stores (drain lazily; no barrier touches vmcnt) ----
    float* pp = d_out + 524289 + gb;
    float* pl = pp + 67108864;
#pragma unroll
    for (int i = 0; i < 4; ++i) {
      f32x4 pv, lpv;
#pragma unroll
      for (int r = 0; r < 4; ++r) {
        lpv[r] = lv[i][r] - c1;
        pv[r]  = __expf(lpv[r]);
      }
      *(f32x4*)(pp + i * 16) = pv;
      *(f32x4*)(pl + i * 16) = lpv;
    }
  }

  // ---- zq cross-wave reduce + partial write ----
  __syncthreads();
#pragma unroll
  for (int m = 0; m < 4; ++m)
    *(f32x4*)(lds + wave * 4096 + l15 * 256 + m * 64 + g4 * 16) = zacc[m];
  __syncthreads();
  const int e = tid * 2;
  f32x2 acc = {0.f, 0.f};
#pragma unroll
  for (int w = 0; w < 8; ++w) acc += *(const f32x2*)(lds + w * 4096 + e * 4);
  *(f32x2*)(ws + WS_ZQP + (unsigned)kg * (1u << 21) +
            (((unsigned)(b * 1024 + n0)) * 64 + e) * 4) = acc;
}

extern "C" void kernel_launch(void* const* d_in, const int* in_sizes, int n_in,
                              void* d_out, int out_size, void* d_ws, size_t ws_size,
                              hipStream_t stream) {
  (void)in_sizes; (void)n_in; (void)out_size; (void)ws_size;
  const float* ze     = (const float*)d_in[0];
  const float* cprobs = (const float*)d_in[1];
  const float* books  = (const float*)d_in[2];
  const float* lpq    = (const float*)d_in[3];
  const float* gum    = (const float*)d_in[4];
  float* out = (float*)d_out;
  char* ws = (char*)d_ws;
  hipLaunchKernelGGL(prep_ze_k,    dim3(32),   dim3(256), 0, stream, ze, ws);
  hipLaunchKernelGGL(prep_bnorm_k, dim3(32),   dim3(256), 0, stream, books, lpq, ws, out);
  hipLaunchKernelGGL(prep_b1_k,    dim3(256),  dim3(256), 0, stream, books, ws);
  hipLaunchKernelGGL(prep_b2_k,    dim3(256),  dim3(256), 0, stream, books, ws);
  hipLaunchKernelGGL(gvq_main,     dim3(1024), dim3(512), 0, stream, gum, cprobs, lpq, ws, out);
  hipLaunchKernelGGL(zq_red_k,     dim3(512),  dim3(256), 0, stream, ws, out);
}